// Round 5
// baseline (571.363 us; speedup 1.0000x reference)
//
#include <hip/hip_runtime.h>

// Problem constants
#define BN    2400   // B*N
#define NG    4      // groups
#define PIN   32     // in_points
#define DIM   256

// DTYPE: inputs fp32, output fp32 (R1/R2 bisection). Internal ws bf16.
// R5: all GEMMs moved to m97-style 128x128 tile + global_load_lds(16B).
// All GEMM operands pre-converted to bf16 (qv, s_w, q_w up front; Wv_w/Wv2_w
// after p2_cls into the dead YM region). OOB m-rows handled by clamping the
// per-lane GLOBAL address (LDS side of global_load_lds is wave-uniform+lane*16,
// global side is per-lane scatter).

typedef __attribute__((ext_vector_type(8))) short bf16x8;
typedef __attribute__((ext_vector_type(4))) short bf16x4;
typedef __attribute__((ext_vector_type(4))) float f32x4;

__device__ __forceinline__ float b2f(unsigned short u) {
    union { unsigned int i; float f; } v; v.i = ((unsigned int)u) << 16; return v.f;
}
__device__ __forceinline__ unsigned short f2b(float f) {
    union { float f; unsigned int i; } v; v.f = f;
    unsigned int x = v.i;
    return (unsigned short)((x + 0x7fffu + ((x >> 16) & 1u)) >> 16);  // RNE
}

__device__ __forceinline__ void gld_lds16(const void* g, void* l) {
    __builtin_amdgcn_global_load_lds(
        (const __attribute__((address_space(1))) unsigned int*)g,
        (__attribute__((address_space(3))) unsigned int*)l, 16, 0, 0);
}

// Block-wide mean/rsqrt(var) over values each thread contributes.
__device__ __forceinline__ void block_stats(float s, float q, float* sRed, int tid,
                                            float inv_n, float& mean, float& istd) {
    #pragma unroll
    for (int off = 32; off > 0; off >>= 1) {
        s += __shfl_down(s, off, 64);
        q += __shfl_down(q, off, 64);
    }
    if ((tid & 63) == 0) { sRed[(tid >> 6) * 2] = s; sRed[(tid >> 6) * 2 + 1] = q; }
    __syncthreads();
    if (tid == 0) {
        float ts = 0.f, tq = 0.f;
        for (int w = 0; w < 4; ++w) { ts += sRed[2 * w]; tq += sRed[2 * w + 1]; }
        float m = ts * inv_n;
        float var = tq * inv_n - m * m;
        sRed[8] = m; sRed[9] = rsqrtf(var + 1e-5f);
    }
    __syncthreads();
    mean = sRed[8]; istd = sRed[9];
}

// ---------------------------------------------------------------------------
// Weight prep A: fp32 -> bf16 with row permutation (g,c,d)->(g,d,c) + bias perm.
// ---------------------------------------------------------------------------
__global__ __launch_bounds__(256) void prep_perm_kernel(
    const float* __restrict__ w, const float* __restrict__ b,
    unsigned short* __restrict__ wOut, float* __restrict__ bOut)
{
    const int row_o = blockIdx.x * 4 + (threadIdx.x >> 6);
    const int lane = threadIdx.x & 63;
    const int g = row_o >> 12, d = (row_o >> 6) & 63, c = row_o & 63;
    const int row_i = (g << 12) + c * 64 + d;
    const float4 x = *(const float4*)(w + (size_t)row_i * 256 + lane * 4);
    bf16x4 pk;
    pk[0] = (short)f2b(x.x); pk[1] = (short)f2b(x.y);
    pk[2] = (short)f2b(x.z); pk[3] = (short)f2b(x.w);
    *(bf16x4*)(wOut + (size_t)row_o * 256 + lane * 4) = pk;
    if (lane == 0) bOut[row_o] = b[row_i];
}

// ---------------------------------------------------------------------------
// Weight prep B: flat fp32 -> bf16 convert, up to 3 tensors via blockIdx.y.
// ---------------------------------------------------------------------------
__global__ __launch_bounds__(256) void prep_flat_kernel(
    const float* __restrict__ a0, unsigned short* __restrict__ o0, int n0,
    const float* __restrict__ a1, unsigned short* __restrict__ o1, int n1,
    const float* __restrict__ a2, unsigned short* __restrict__ o2, int n2)
{
    const float* src; unsigned short* dst; int n;
    if (blockIdx.y == 0)      { src = a0; dst = o0; n = n0; }
    else if (blockIdx.y == 1) { src = a1; dst = o1; n = n1; }
    else                      { src = a2; dst = o2; n = n2; }
    const int idx = (blockIdx.x * 256 + threadIdx.x) * 8;
    if (idx >= n) return;
    float4 x0 = ((const float4*)(src + idx))[0];
    float4 x1 = ((const float4*)(src + idx))[1];
    bf16x8 v;
    v[0]=(short)f2b(x0.x); v[1]=(short)f2b(x0.y); v[2]=(short)f2b(x0.z); v[3]=(short)f2b(x0.w);
    v[4]=(short)f2b(x1.x); v[5]=(short)f2b(x1.y); v[6]=(short)f2b(x1.z); v[7]=(short)f2b(x1.w);
    *(bf16x8*)(dst + idx) = v;
}

// ---------------------------------------------------------------------------
// m97-style NT GEMM: C(MxN) = A(MxK) * W(NxK)^T (+bias). All-bf16 operands.
// 128x128 tile, BK=64, unpadded LDS, global_load_lds dwordx4 staging.
// 4 waves in 2x2; each computes 64x64 via 4x4 MFMA 16x16x32_bf16.
// OUT_MODE 0: bf16 out (+fp32 bias). OUT_MODE 2: fp32 split-K partial at
//             Cout + blockIdx.z*M*N, no bias. kLen = K-span per z-slice.
// OOB m-rows: global addr clamped to M-1 (valid reads, stores masked).
// ---------------------------------------------------------------------------
template<int OUT_MODE>
__global__ __launch_bounds__(256) void gemm_big_kernel(
    const unsigned short* __restrict__ A,
    const unsigned short* __restrict__ W,
    const float* __restrict__ bias,
    void* __restrict__ Cout,
    int M, int N, int ldK, int kLen)
{
    __shared__ __attribute__((aligned(16))) short sA[128 * 64];
    __shared__ __attribute__((aligned(16))) short sB[128 * 64];

    const int m0 = blockIdx.x * 128;
    const int n0 = blockIdx.y * 128;
    const int tid = threadIdx.x;
    const int lane = tid & 63;
    const int wave = tid >> 6;
    const int l16 = lane & 15;
    const int quad = lane >> 4;
    const int wr = (wave >> 1) * 64;
    const int wc = (wave & 1) * 64;

    f32x4 acc[4][4] = {};

    const int kbase = blockIdx.z * kLen;
    for (int k0 = kbase; k0 < kbase + kLen; k0 += 64) {
        // stage 16KB per matrix: 256 thr x 16B x 4 rounds; LDS side is
        // wave-uniform base + lane*16 (f = r*256 + wave*64 + lane).
        #pragma unroll
        for (int r = 0; r < 4; ++r) {
            const int f = r * 256 + tid;
            const int row = f >> 3, ch = (f & 7) * 8;
            int gr = m0 + row; if (gr >= M) gr = M - 1;
            gld_lds16(A + (size_t)gr * ldK + k0 + ch, (char*)sA + f * 16);
            gld_lds16(W + (size_t)(n0 + row) * ldK + k0 + ch, (char*)sB + f * 16);
        }
        __syncthreads();
        #pragma unroll
        for (int ks = 0; ks < 64; ks += 32) {
            bf16x8 a[4], b[4];
            #pragma unroll
            for (int mi = 0; mi < 4; ++mi)
                a[mi] = *(const bf16x8*)(sA + (wr + mi * 16 + l16) * 64 + ks + quad * 8);
            #pragma unroll
            for (int ni = 0; ni < 4; ++ni)
                b[ni] = *(const bf16x8*)(sB + (wc + ni * 16 + l16) * 64 + ks + quad * 8);
            #pragma unroll
            for (int mi = 0; mi < 4; ++mi)
                #pragma unroll
                for (int ni = 0; ni < 4; ++ni)
                    acc[mi][ni] = __builtin_amdgcn_mfma_f32_16x16x32_bf16(
                        a[mi], b[ni], acc[mi][ni], 0, 0, 0);
        }
        __syncthreads();
    }

    // epilogue: D layout col=l16, row=quad*4+r [m89/m91]
    #pragma unroll
    for (int mi = 0; mi < 4; ++mi) {
        #pragma unroll
        for (int r = 0; r < 4; ++r) {
            const int row = m0 + wr + mi * 16 + quad * 4 + r;
            if (row >= M) continue;
            #pragma unroll
            for (int ni = 0; ni < 4; ++ni) {
                const int col = n0 + wc + ni * 16 + l16;
                if (OUT_MODE == 0) {
                    const float bv = bias ? bias[col] : 0.0f;
                    ((unsigned short*)Cout)[(size_t)row * N + col] = f2b(acc[mi][ni][r] + bv);
                } else {
                    float* o = (float*)Cout + (size_t)blockIdx.z * M * N;
                    o[(size_t)row * N + col] = acc[mi][ni][r];
                }
            }
        }
    }
}

// ---------------------------------------------------------------------------
// Phase 2 reg (MFMA): per (t,g): fMS = relu(LN2d(S @ relu(LN2d(f @ M))))
// ---------------------------------------------------------------------------
__global__ __launch_bounds__(256) void p2_reg_kernel(
    const float* __restrict__ feats,           // (BN,G,32,64) fp32
    const unsigned short* __restrict__ YM,     // (BN,16384) bf16: g*4096 + d*64 + c
    const unsigned short* __restrict__ YS,     // (BN,4096)  bf16: g*1024 + o*32 + p
    unsigned short* __restrict__ FMS)          // (BN,8192)  bf16: g*2048 + o*64 + d
{
    const int t = blockIdx.x, g = blockIdx.y;
    const int tid = threadIdx.x;
    const int wave = tid >> 6, lane = tid & 63;
    const int l16 = lane & 15, quad = lane >> 4;

    __shared__ short fB[32][72];
    __shared__ short Mt[64][72];
    __shared__ short sS[32][40];
    __shared__ short X1T[64][40];
    __shared__ float sRed[16];

    {
        const float* fp = feats + (size_t)(t * NG + g) * 2048 + tid * 8;
        float4 x0 = ((const float4*)fp)[0];
        float4 x1 = ((const float4*)fp)[1];
        bf16x8 v;
        v[0]=(short)f2b(x0.x); v[1]=(short)f2b(x0.y); v[2]=(short)f2b(x0.z); v[3]=(short)f2b(x0.w);
        v[4]=(short)f2b(x1.x); v[5]=(short)f2b(x1.y); v[6]=(short)f2b(x1.z); v[7]=(short)f2b(x1.w);
        *(bf16x8*)(&fB[tid >> 3][(tid & 7) * 8]) = v;
    }
    {
        const unsigned short* mp = YM + (size_t)t * 16384 + g * 4096 + tid * 16;
        bf16x8 v0 = ((const bf16x8*)mp)[0];
        bf16x8 v1 = ((const bf16x8*)mp)[1];
        const int d = tid >> 2, c0 = (tid & 3) * 16;
        *(bf16x8*)(&Mt[d][c0])     = v0;
        *(bf16x8*)(&Mt[d][c0 + 8]) = v1;
    }
    {
        const unsigned short* sp = YS + (size_t)t * 4096 + g * 1024 + tid * 4;
        *(bf16x4*)(&sS[tid >> 3][(tid & 7) * 4]) = *(const bf16x4*)sp;
    }
    __syncthreads();

    f32x4 accA[2] = {};
    #pragma unroll
    for (int ks = 0; ks < 64; ks += 32) {
        bf16x8 b = *(const bf16x8*)(&Mt[wave * 16 + l16][ks + quad * 8]);
        #pragma unroll
        for (int mt = 0; mt < 2; ++mt) {
            bf16x8 a = *(const bf16x8*)(&fB[mt * 16 + l16][ks + quad * 8]);
            accA[mt] = __builtin_amdgcn_mfma_f32_16x16x32_bf16(a, b, accA[mt], 0, 0, 0);
        }
    }
    float ls = 0.f, lq = 0.f;
    #pragma unroll
    for (int mt = 0; mt < 2; ++mt)
        #pragma unroll
        for (int r = 0; r < 4; ++r) { float v = accA[mt][r]; ls += v; lq += v * v; }
    float mean, istd;
    block_stats(ls, lq, sRed, tid, 1.0f / 2048.0f, mean, istd);
    #pragma unroll
    for (int mt = 0; mt < 2; ++mt) {
        bf16x4 pk;
        #pragma unroll
        for (int r = 0; r < 4; ++r) {
            float y = (accA[mt][r] - mean) * istd;
            pk[r] = (short)f2b(y > 0.f ? y : 0.f);
        }
        *(bf16x4*)(&X1T[wave * 16 + l16][mt * 16 + quad * 4]) = pk;
    }
    __syncthreads();

    f32x4 accB[2] = {};
    {
        bf16x8 b = *(const bf16x8*)(&X1T[wave * 16 + l16][quad * 8]);
        #pragma unroll
        for (int mt = 0; mt < 2; ++mt) {
            bf16x8 a = *(const bf16x8*)(&sS[mt * 16 + l16][quad * 8]);
            accB[mt] = __builtin_amdgcn_mfma_f32_16x16x32_bf16(a, b, accB[mt], 0, 0, 0);
        }
    }
    ls = 0.f; lq = 0.f;
    #pragma unroll
    for (int mt = 0; mt < 2; ++mt)
        #pragma unroll
        for (int r = 0; r < 4; ++r) { float v = accB[mt][r]; ls += v; lq += v * v; }
    block_stats(ls, lq, sRed, tid, 1.0f / 2048.0f, mean, istd);

    unsigned short* outp = FMS + (size_t)t * 8192 + g * 2048;
    const int d = wave * 16 + l16;
    #pragma unroll
    for (int mt = 0; mt < 2; ++mt)
        #pragma unroll
        for (int r = 0; r < 4; ++r) {
            float y = (accB[mt][r] - mean) * istd;
            outp[(mt * 16 + quad * 4 + r) * 64 + d] = f2b(y > 0.f ? y : 0.f);
        }
}

// ---------------------------------------------------------------------------
// Phase 2 cls (MFMA): v = relu(LN2d(f@vW)); k = kw·v^T + kb;
// sc = softmax(q@k/8); fc = relu(LN2d(sc@v))
// ---------------------------------------------------------------------------
__global__ __launch_bounds__(256) void p2_cls_kernel(
    const float* __restrict__ feats,
    const unsigned short* __restrict__ YV,     // (BN,16384) bf16 [g][d][c]
    const unsigned short* __restrict__ YQ,     // (BN,4096)  bf16 [g][o][i]
    const float* __restrict__ kwp,             // (128,64) fp32
    const float* __restrict__ kbp,             // (128) fp32
    unsigned short* __restrict__ FC)
{
    const int t = blockIdx.x, g = blockIdx.y;
    const int tid = threadIdx.x;
    const int wave = tid >> 6, lane = tid & 63;
    const int l16 = lane & 15, quad = lane >> 4;

    __shared__ short fB[32][72];
    __shared__ short Vt[64][72];
    __shared__ short kw[32][72];
    __shared__ short vRM[32][72];
    __shared__ short vT[64][40];
    __shared__ short kT[32][40];
    __shared__ short sQ[32][40];
    __shared__ short sSC[32][40];
    __shared__ float sKB[32];
    __shared__ float sRed[16];

    {
        const float* fp = feats + (size_t)(t * NG + g) * 2048 + tid * 8;
        float4 x0 = ((const float4*)fp)[0];
        float4 x1 = ((const float4*)fp)[1];
        bf16x8 v;
        v[0]=(short)f2b(x0.x); v[1]=(short)f2b(x0.y); v[2]=(short)f2b(x0.z); v[3]=(short)f2b(x0.w);
        v[4]=(short)f2b(x1.x); v[5]=(short)f2b(x1.y); v[6]=(short)f2b(x1.z); v[7]=(short)f2b(x1.w);
        *(bf16x8*)(&fB[tid >> 3][(tid & 7) * 8]) = v;
    }
    {
        const unsigned short* mp = YV + (size_t)t * 16384 + g * 4096 + tid * 16;
        bf16x8 v0 = ((const bf16x8*)mp)[0];
        bf16x8 v1 = ((const bf16x8*)mp)[1];
        const int d = tid >> 2, c0 = (tid & 3) * 16;
        *(bf16x8*)(&Vt[d][c0])     = v0;
        *(bf16x8*)(&Vt[d][c0 + 8]) = v1;
    }
    {
        const float* kp = kwp + (size_t)g * 2048 + tid * 8;
        float4 x0 = ((const float4*)kp)[0];
        float4 x1 = ((const float4*)kp)[1];
        bf16x8 v;
        v[0]=(short)f2b(x0.x); v[1]=(short)f2b(x0.y); v[2]=(short)f2b(x0.z); v[3]=(short)f2b(x0.w);
        v[4]=(short)f2b(x1.x); v[5]=(short)f2b(x1.y); v[6]=(short)f2b(x1.z); v[7]=(short)f2b(x1.w);
        *(bf16x8*)(&kw[tid >> 3][(tid & 7) * 8]) = v;
    }
    {
        const unsigned short* qp = YQ + (size_t)t * 4096 + g * 1024 + tid * 4;
        *(bf16x4*)(&sQ[tid >> 3][(tid & 7) * 4]) = *(const bf16x4*)qp;
    }
    if (tid < 32) sKB[tid] = kbp[g * 32 + tid];
    __syncthreads();

    f32x4 accA[2] = {};
    #pragma unroll
    for (int ks = 0; ks < 64; ks += 32) {
        bf16x8 b = *(const bf16x8*)(&Vt[wave * 16 + l16][ks + quad * 8]);
        #pragma unroll
        for (int mt = 0; mt < 2; ++mt) {
            bf16x8 a = *(const bf16x8*)(&fB[mt * 16 + l16][ks + quad * 8]);
            accA[mt] = __builtin_amdgcn_mfma_f32_16x16x32_bf16(a, b, accA[mt], 0, 0, 0);
        }
    }
    float ls = 0.f, lq = 0.f;
    #pragma unroll
    for (int mt = 0; mt < 2; ++mt)
        #pragma unroll
        for (int r = 0; r < 4; ++r) { float v = accA[mt][r]; ls += v; lq += v * v; }
    float mean, istd;
    block_stats(ls, lq, sRed, tid, 1.0f / 2048.0f, mean, istd);
    {
        const int d = wave * 16 + l16;
        #pragma unroll
        for (int mt = 0; mt < 2; ++mt) {
            bf16x4 pk;
            #pragma unroll
            for (int r = 0; r < 4; ++r) {
                float y = (accA[mt][r] - mean) * istd;
                unsigned short u = f2b(y > 0.f ? y : 0.f);
                pk[r] = (short)u;
                vRM[mt * 16 + quad * 4 + r][d] = (short)u;
            }
            *(bf16x4*)(&vT[d][mt * 16 + quad * 4]) = pk;
        }
    }
    __syncthreads();

    {   // k[i][p] = kw[i]·v[p] + kb
        const int it = wave >> 1, pt = wave & 1;
        f32x4 accK = {};
        #pragma unroll
        for (int ks = 0; ks < 64; ks += 32) {
            bf16x8 a = *(const bf16x8*)(&kw[it * 16 + l16][ks + quad * 8]);
            bf16x8 b = *(const bf16x8*)(&vRM[pt * 16 + l16][ks + quad * 8]);
            accK = __builtin_amdgcn_mfma_f32_16x16x32_bf16(a, b, accK, 0, 0, 0);
        }
        bf16x4 pk;
        #pragma unroll
        for (int r = 0; r < 4; ++r)
            pk[r] = (short)f2b(accK[r] + sKB[it * 16 + quad * 4 + r]);
        *(bf16x4*)(&kT[pt * 16 + l16][it * 16 + quad * 4]) = pk;
    }
    __syncthreads();

    if (wave < 2) {   // logits + softmax
        f32x4 accL[2] = {};
        bf16x8 a = *(const bf16x8*)(&sQ[wave * 16 + l16][quad * 8]);
        #pragma unroll
        for (int pt = 0; pt < 2; ++pt) {
            bf16x8 b = *(const bf16x8*)(&kT[pt * 16 + l16][quad * 8]);
            accL[pt] = __builtin_amdgcn_mfma_f32_16x16x32_bf16(a, b, accL[pt], 0, 0, 0);
        }
        #pragma unroll
        for (int r = 0; r < 4; ++r) {
            float a0 = accL[0][r] * 0.125f, a1 = accL[1][r] * 0.125f;
            float mx = fmaxf(a0, a1);
            #pragma unroll
            for (int m = 1; m < 16; m <<= 1) mx = fmaxf(mx, __shfl_xor(mx, m, 64));
            a0 = __expf(a0 - mx); a1 = __expf(a1 - mx);
            float sum = a0 + a1;
            #pragma unroll
            for (int m = 1; m < 16; m <<= 1) sum += __shfl_xor(sum, m, 64);
            const float inv_s = 1.0f / sum;
            const int o = wave * 16 + quad * 4 + r;
            sSC[o][l16]      = (short)f2b(a0 * inv_s);
            sSC[o][16 + l16] = (short)f2b(a1 * inv_s);
        }
    }
    __syncthreads();

    f32x4 accB[2] = {};
    {
        bf16x8 b = *(const bf16x8*)(&vT[wave * 16 + l16][quad * 8]);
        #pragma unroll
        for (int mt = 0; mt < 2; ++mt) {
            bf16x8 a = *(const bf16x8*)(&sSC[mt * 16 + l16][quad * 8]);
            accB[mt] = __builtin_amdgcn_mfma_f32_16x16x32_bf16(a, b, accB[mt], 0, 0, 0);
        }
    }
    ls = 0.f; lq = 0.f;
    #pragma unroll
    for (int mt = 0; mt < 2; ++mt)
        #pragma unroll
        for (int r = 0; r < 4; ++r) { float v = accB[mt][r]; ls += v; lq += v * v; }
    block_stats(ls, lq, sRed, tid, 1.0f / 2048.0f, mean, istd);

    unsigned short* outp = FC + (size_t)t * 8192 + g * 2048;
    const int d = wave * 16 + l16;
    #pragma unroll
    for (int mt = 0; mt < 2; ++mt)
        #pragma unroll
        for (int r = 0; r < 4; ++r) {
            float y = (accB[mt][r] - mean) * istd;
            outp[(mt * 16 + quad * 4 + r) * 64 + d] = f2b(y > 0.f ? y : 0.f);
        }
}

// ---------------------------------------------------------------------------
// Final: reduce split-K partials, residual add, affine LN over 256, fp32 out.
// ---------------------------------------------------------------------------
__global__ __launch_bounds__(256) void final_ln_kernel(
    const float* __restrict__ qv,
    const float* __restrict__ MSP,   // (8, BN, 256) fp32 partials
    const float* __restrict__ CLP,
    const float* __restrict__ Wv_b,
    const float* __restrict__ Wv2_b,
    const float* __restrict__ lnA_w,
    const float* __restrict__ lnA_b,
    const float* __restrict__ lnB_w,
    const float* __restrict__ lnB_b,
    float* __restrict__ out)
{
    __shared__ float sRed[16];
    const int t = blockIdx.x;
    const int br = blockIdx.y;
    const int c = threadIdx.x;
    const float* P = br ? CLP : MSP;
    const float* bias = br ? Wv2_b : Wv_b;
    const float* lw = br ? lnB_w : lnA_w;
    const float* lb = br ? lnB_b : lnA_b;

    float x = qv[t * 256 + c] + bias[c];
    #pragma unroll
    for (int s = 0; s < 8; ++s) x += P[(size_t)s * (BN * 256) + t * 256 + c];

    float mean, istd;
    block_stats(x, x * x, sRed, c, 1.0f / 256.0f, mean, istd);
    out[(size_t)br * (BN * 256) + t * 256 + c] = (x - mean) * istd * lw[c] + lb[c];
}

// ---------------------------------------------------------------------------
extern "C" void kernel_launch(void* const* d_in, const int* in_sizes, int n_in,
                              void* d_out, int out_size, void* d_ws, size_t ws_size,
                              hipStream_t stream) {
    const float* feats = (const float*)d_in[0];
    const float* qv    = (const float*)d_in[1];
    const float* m_w   = (const float*)d_in[7];
    const float* m_b   = (const float*)d_in[8];
    const float* s_w   = (const float*)d_in[9];
    const float* s_b   = (const float*)d_in[10];
    const float* q_w   = (const float*)d_in[11];
    const float* q_b   = (const float*)d_in[12];
    const float* v_w   = (const float*)d_in[13];
    const float* v_b   = (const float*)d_in[14];
    const float* k_w   = (const float*)d_in[15];
    const float* k_b   = (const float*)d_in[16];
    const float* Wv_w  = (const float*)d_in[17];
    const float* Wv_b  = (const float*)d_in[18];
    const float* Wv2_w = (const float*)d_in[19];
    const float* Wv2_b = (const float*)d_in[20];
    const float* lnA_w = (const float*)d_in[21];
    const float* lnA_b = (const float*)d_in[22];
    const float* lnB_w = (const float*)d_in[23];
    const float* lnB_b = (const float*)d_in[24];

    char* ws = (char*)d_ws;
    // Workspace (176.9 MB peak, unchanged from R4):
    //  [0, 78.6M)      YM  (gen M/V out) -> later MSP/CLP + WvB/Wv2B
    //  [78.6M, 98.3M)  YS
    //  [98.3M, 137.6M) FMS
    //  [137.6M, 176.9M) FC; transient preps live here until p2_cls
    const size_t OFF_YM  = 0;
    const size_t OFF_YS  = 78643200;
    const size_t OFF_FMS = 98304000;
    const size_t OFF_FC  = 137625600;

    unsigned short* YM  = (unsigned short*)(ws + OFF_YM);
    unsigned short* YS  = (unsigned short*)(ws + OFF_YS);
    unsigned short* FMS = (unsigned short*)(ws + OFF_FMS);
    unsigned short* FC  = (unsigned short*)(ws + OFF_FC);
    // transient preps in FC slot (22.4 MB <= 39.3 MB; all dead before p2_cls)
    unsigned short* m_wP = (unsigned short*)(ws + OFF_FC);              //  8,388,608
    unsigned short* v_wP = (unsigned short*)(ws + OFF_FC + 8388608);    //  8,388,608
    unsigned short* s_wB = (unsigned short*)(ws + OFF_FC + 16777216);   //  2,097,152
    unsigned short* q_wB = (unsigned short*)(ws + OFF_FC + 18874368);   //  2,097,152
    unsigned short* qv_B = (unsigned short*)(ws + OFF_FC + 20971520);   //  1,228,800
    float* m_bP = (float*)(ws + OFF_FC + 22200320);                     //     65,536
    float* v_bP = (float*)(ws + OFF_FC + 22265856);                     //     65,536
    // post-p2_cls region (YM dead): splitK=8 partials + bf16 proj weights
    float* MSP = (float*)(ws + 0);                                      // 19,660,800
    float* CLP = (float*)(ws + 19660800);                               // 19,660,800
    unsigned short* WvB  = (unsigned short*)(ws + 39321600);            //  4,194,304
    unsigned short* Wv2B = (unsigned short*)(ws + 43515904);            //  4,194,304

    const dim3 blk(256);
    // preps: permute+cvt m_w/v_w; flat-cvt s_w/q_w/qv
    prep_perm_kernel<<<4096, blk, 0, stream>>>(m_w, m_b, m_wP, m_bP);
    prep_perm_kernel<<<4096, blk, 0, stream>>>(v_w, v_b, v_wP, v_bP);
    prep_flat_kernel<<<dim3(2048, 3), blk, 0, stream>>>(
        s_w, s_wB, 4096 * 256, q_w, q_wB, 4096 * 256, qv, qv_B, BN * 256);
    // reg branch
    gemm_big_kernel<0><<<dim3(19, 128, 1), blk, 0, stream>>>(qv_B, m_wP, m_bP, YM, BN, 16384, 256, 256);
    gemm_big_kernel<0><<<dim3(19, 32, 1),  blk, 0, stream>>>(qv_B, s_wB, s_b, YS, BN, 4096, 256, 256);
    p2_reg_kernel<<<dim3(BN, NG), blk, 0, stream>>>(feats, YM, YS, FMS);
    // cls branch (reuse YM/YS)
    gemm_big_kernel<0><<<dim3(19, 128, 1), blk, 0, stream>>>(qv_B, v_wP, v_bP, YM, BN, 16384, 256, 256);
    gemm_big_kernel<0><<<dim3(19, 32, 1),  blk, 0, stream>>>(qv_B, q_wB, q_b, YS, BN, 4096, 256, 256);
    p2_cls_kernel<<<dim3(BN, NG), blk, 0, stream>>>(feats, YM, YS, k_w, k_b, FC);
    // proj weights -> bf16 into dead YM region, then 128-tile splitK=8 projections
    prep_flat_kernel<<<dim3(1024, 2), blk, 0, stream>>>(
        Wv_w, WvB, 256 * 8192, Wv2_w, Wv2B, 256 * 8192, nullptr, nullptr, 0);
    gemm_big_kernel<2><<<dim3(19, 2, 8), blk, 0, stream>>>(FMS, WvB,  nullptr, MSP, BN, 256, 8192, 1024);
    gemm_big_kernel<2><<<dim3(19, 2, 8), blk, 0, stream>>>(FC,  Wv2B, nullptr, CLP, BN, 256, 8192, 1024);
    final_ln_kernel<<<dim3(BN, 2), blk, 0, stream>>>(qv, MSP, CLP, Wv_b, Wv2_b,
                                                     lnA_w, lnA_b, lnB_w, lnB_b,
                                                     (float*)d_out);
}

// Round 6
// 463.958 us; speedup vs baseline: 1.2315x; 1.2315x over previous
//
#include <hip/hip_runtime.h>

// Problem constants
#define BN    2400   // B*N
#define NG    4      // groups
#define PIN   32     // in_points
#define DIM   256

// DTYPE: inputs fp32, output fp32. Internal ws bf16.
// R6: revert to R4 64x64 padded-LDS GEMM (R5's m97-style 128-tile regressed:
// K=256 -> only 4 k-iters, occupancy 20%, barrier drain unhidden).
// Keep R5's bf16 pre-conversion (staging loses the f2b VALU work), and fuse
// M+S / V+Q generator GEMMs into single N=20480 launches.

typedef __attribute__((ext_vector_type(8))) short bf16x8;
typedef __attribute__((ext_vector_type(4))) short bf16x4;
typedef __attribute__((ext_vector_type(4))) float f32x4;

__device__ __forceinline__ float b2f(unsigned short u) {
    union { unsigned int i; float f; } v; v.i = ((unsigned int)u) << 16; return v.f;
}
__device__ __forceinline__ unsigned short f2b(float f) {
    union { float f; unsigned int i; } v; v.f = f;
    unsigned int x = v.i;
    return (unsigned short)((x + 0x7fffu + ((x >> 16) & 1u)) >> 16);  // RNE
}

// Block-wide mean/rsqrt(var) over values each thread contributes.
__device__ __forceinline__ void block_stats(float s, float q, float* sRed, int tid,
                                            float inv_n, float& mean, float& istd) {
    #pragma unroll
    for (int off = 32; off > 0; off >>= 1) {
        s += __shfl_down(s, off, 64);
        q += __shfl_down(q, off, 64);
    }
    if ((tid & 63) == 0) { sRed[(tid >> 6) * 2] = s; sRed[(tid >> 6) * 2 + 1] = q; }
    __syncthreads();
    if (tid == 0) {
        float ts = 0.f, tq = 0.f;
        for (int w = 0; w < 4; ++w) { ts += sRed[2 * w]; tq += sRed[2 * w + 1]; }
        float m = ts * inv_n;
        float var = tq * inv_n - m * m;
        sRed[8] = m; sRed[9] = rsqrtf(var + 1e-5f);
    }
    __syncthreads();
    mean = sRed[8]; istd = sRed[9];
}

// ---------------------------------------------------------------------------
// Weight prep A: fp32 -> bf16 with row permutation (g,c,d)->(g,d,c) + bias perm.
// ---------------------------------------------------------------------------
__global__ __launch_bounds__(256) void prep_perm_kernel(
    const float* __restrict__ w, const float* __restrict__ b,
    unsigned short* __restrict__ wOut, float* __restrict__ bOut)
{
    const int row_o = blockIdx.x * 4 + (threadIdx.x >> 6);
    const int lane = threadIdx.x & 63;
    const int g = row_o >> 12, d = (row_o >> 6) & 63, c = row_o & 63;
    const int row_i = (g << 12) + c * 64 + d;
    const float4 x = *(const float4*)(w + (size_t)row_i * 256 + lane * 4);
    bf16x4 pk;
    pk[0] = (short)f2b(x.x); pk[1] = (short)f2b(x.y);
    pk[2] = (short)f2b(x.z); pk[3] = (short)f2b(x.w);
    *(bf16x4*)(wOut + (size_t)row_o * 256 + lane * 4) = pk;
    if (lane == 0) bOut[row_o] = b[row_i];
}

// ---------------------------------------------------------------------------
// Weight prep B: flat fp32 -> bf16 convert, up to 3 tensors via blockIdx.y.
// ---------------------------------------------------------------------------
__global__ __launch_bounds__(256) void prep_flat_kernel(
    const float* __restrict__ a0, unsigned short* __restrict__ o0, int n0,
    const float* __restrict__ a1, unsigned short* __restrict__ o1, int n1,
    const float* __restrict__ a2, unsigned short* __restrict__ o2, int n2)
{
    const float* src; unsigned short* dst; int n;
    if (blockIdx.y == 0)      { src = a0; dst = o0; n = n0; }
    else if (blockIdx.y == 1) { src = a1; dst = o1; n = n1; }
    else                      { src = a2; dst = o2; n = n2; }
    const int idx = (blockIdx.x * 256 + threadIdx.x) * 8;
    if (idx >= n) return;
    float4 x0 = ((const float4*)(src + idx))[0];
    float4 x1 = ((const float4*)(src + idx))[1];
    bf16x8 v;
    v[0]=(short)f2b(x0.x); v[1]=(short)f2b(x0.y); v[2]=(short)f2b(x0.z); v[3]=(short)f2b(x0.w);
    v[4]=(short)f2b(x1.x); v[5]=(short)f2b(x1.y); v[6]=(short)f2b(x1.z); v[7]=(short)f2b(x1.w);
    *(bf16x8*)(dst + idx) = v;
}

// Bias copy fp32->fp32 (4096 elems each, two pairs via blockIdx.y).
__global__ __launch_bounds__(256) void copy_bias_kernel(
    const float* __restrict__ a0, float* __restrict__ o0,
    const float* __restrict__ a1, float* __restrict__ o1)
{
    const int i = blockIdx.x * 256 + threadIdx.x;
    if (blockIdx.y == 0) o0[i] = a0[i]; else o1[i] = a1[i];
}

// ---------------------------------------------------------------------------
// NT GEMM (R4 structure): C(MxN) = A(MxK) * W(NxK)^T (+bias), all-bf16 in.
// Tile 64x64, padded LDS (+8 -> 4-bank row rotation, ~2-way conflicts = free),
// 4 waves x (2x2) MFMA 16x16x32_bf16. 8 blocks/CU (18KB LDS) for latency hiding.
// OUT_MODE 0: bf16 out (+fp32 bias). OUT_MODE 2: fp32 split-K partial at
//             Cout + blockIdx.z*M*N, no bias. kLen = K-span per z-slice.
// ---------------------------------------------------------------------------
template<int OUT_MODE>
__global__ __launch_bounds__(256) void gemm_nt_kernel(
    const unsigned short* __restrict__ A,
    const unsigned short* __restrict__ W,
    const float* __restrict__ bias,
    void* __restrict__ Cout,
    int M, int N, int ldK, int kLen)
{
    __shared__ short sA[64][72];
    __shared__ short sB[64][72];

    const int m0 = blockIdx.x * 64;
    const int n0 = blockIdx.y * 64;
    const int tid = threadIdx.x;
    const int lane = tid & 63;
    const int wave = tid >> 6;
    const int l16 = lane & 15;
    const int quad = lane >> 4;
    const int wr = (wave >> 1) * 32;
    const int wc = (wave & 1) * 32;

    const int lr = tid >> 2;            // row 0..63
    const int lc = (tid & 3) * 16;      // col 0,16,32,48

    f32x4 acc[2][2] = {};

    const int kbase = blockIdx.z * kLen;
    for (int k0 = kbase; k0 < kbase + kLen; k0 += 64) {
        {   // stage A (bf16, 2x16B per thread)
            const int gr = m0 + lr;
            bf16x8 a0 = {}, a1 = {};
            if (gr < M) {
                const unsigned short* ap = A + (size_t)gr * ldK + k0 + lc;
                a0 = ((const bf16x8*)ap)[0];
                a1 = ((const bf16x8*)ap)[1];
            }
            *(bf16x8*)(&sA[lr][lc])     = a0;
            *(bf16x8*)(&sA[lr][lc + 8]) = a1;
            // stage W (N multiple of 64 -> no guard)
            const unsigned short* wp = W + (size_t)(n0 + lr) * ldK + k0 + lc;
            *(bf16x8*)(&sB[lr][lc])     = ((const bf16x8*)wp)[0];
            *(bf16x8*)(&sB[lr][lc + 8]) = ((const bf16x8*)wp)[1];
        }
        __syncthreads();
        #pragma unroll
        for (int ks = 0; ks < 64; ks += 32) {
            bf16x8 a0 = *(const bf16x8*)(&sA[wr + l16][ks + quad * 8]);
            bf16x8 a1 = *(const bf16x8*)(&sA[wr + 16 + l16][ks + quad * 8]);
            bf16x8 b0 = *(const bf16x8*)(&sB[wc + l16][ks + quad * 8]);
            bf16x8 b1 = *(const bf16x8*)(&sB[wc + 16 + l16][ks + quad * 8]);
            acc[0][0] = __builtin_amdgcn_mfma_f32_16x16x32_bf16(a0, b0, acc[0][0], 0, 0, 0);
            acc[0][1] = __builtin_amdgcn_mfma_f32_16x16x32_bf16(a0, b1, acc[0][1], 0, 0, 0);
            acc[1][0] = __builtin_amdgcn_mfma_f32_16x16x32_bf16(a1, b0, acc[1][0], 0, 0, 0);
            acc[1][1] = __builtin_amdgcn_mfma_f32_16x16x32_bf16(a1, b1, acc[1][1], 0, 0, 0);
        }
        __syncthreads();
    }

    // epilogue: D layout col=l16, row=quad*4+r [m89/m91]
    #pragma unroll
    for (int s = 0; s < 2; ++s) {
        #pragma unroll
        for (int u = 0; u < 2; ++u) {
            const int col = n0 + wc + u * 16 + l16;
            const float bv = (OUT_MODE == 0 && bias) ? bias[col] : 0.0f;
            #pragma unroll
            for (int r = 0; r < 4; ++r) {
                const int row = m0 + wr + s * 16 + quad * 4 + r;
                if (row < M) {
                    const float val = acc[s][u][r] + bv;
                    if (OUT_MODE == 0) {
                        ((unsigned short*)Cout)[(size_t)row * N + col] = f2b(val);
                    } else {
                        float* o = (float*)Cout + (size_t)blockIdx.z * M * N;
                        o[(size_t)row * N + col] = val;
                    }
                }
            }
        }
    }
}

// ---------------------------------------------------------------------------
// Phase 2 reg (MFMA): per (t,g): fMS = relu(LN2d(S @ relu(LN2d(f @ M))))
// Y1 row (20480) = [M^T (g*4096 + d*64 + c) x4 | S (16384 + g*1024 + o*32 + p) x4]
// ---------------------------------------------------------------------------
__global__ __launch_bounds__(256) void p2_reg_kernel(
    const float* __restrict__ feats,           // (BN,G,32,64) fp32
    const unsigned short* __restrict__ Y1,     // (BN,20480) bf16
    unsigned short* __restrict__ FMS)          // (BN,8192)  bf16: g*2048 + o*64 + d
{
    const int t = blockIdx.x, g = blockIdx.y;
    const int tid = threadIdx.x;
    const int wave = tid >> 6, lane = tid & 63;
    const int l16 = lane & 15, quad = lane >> 4;

    __shared__ short fB[32][72];
    __shared__ short Mt[64][72];
    __shared__ short sS[32][40];
    __shared__ short X1T[64][40];
    __shared__ float sRed[16];

    {
        const float* fp = feats + (size_t)(t * NG + g) * 2048 + tid * 8;
        float4 x0 = ((const float4*)fp)[0];
        float4 x1 = ((const float4*)fp)[1];
        bf16x8 v;
        v[0]=(short)f2b(x0.x); v[1]=(short)f2b(x0.y); v[2]=(short)f2b(x0.z); v[3]=(short)f2b(x0.w);
        v[4]=(short)f2b(x1.x); v[5]=(short)f2b(x1.y); v[6]=(short)f2b(x1.z); v[7]=(short)f2b(x1.w);
        *(bf16x8*)(&fB[tid >> 3][(tid & 7) * 8]) = v;
    }
    {
        const unsigned short* mp = Y1 + (size_t)t * 20480 + g * 4096 + tid * 16;
        bf16x8 v0 = ((const bf16x8*)mp)[0];
        bf16x8 v1 = ((const bf16x8*)mp)[1];
        const int d = tid >> 2, c0 = (tid & 3) * 16;
        *(bf16x8*)(&Mt[d][c0])     = v0;
        *(bf16x8*)(&Mt[d][c0 + 8]) = v1;
    }
    {
        const unsigned short* sp = Y1 + (size_t)t * 20480 + 16384 + g * 1024 + tid * 4;
        *(bf16x4*)(&sS[tid >> 3][(tid & 7) * 4]) = *(const bf16x4*)sp;
    }
    __syncthreads();

    f32x4 accA[2] = {};
    #pragma unroll
    for (int ks = 0; ks < 64; ks += 32) {
        bf16x8 b = *(const bf16x8*)(&Mt[wave * 16 + l16][ks + quad * 8]);
        #pragma unroll
        for (int mt = 0; mt < 2; ++mt) {
            bf16x8 a = *(const bf16x8*)(&fB[mt * 16 + l16][ks + quad * 8]);
            accA[mt] = __builtin_amdgcn_mfma_f32_16x16x32_bf16(a, b, accA[mt], 0, 0, 0);
        }
    }
    float ls = 0.f, lq = 0.f;
    #pragma unroll
    for (int mt = 0; mt < 2; ++mt)
        #pragma unroll
        for (int r = 0; r < 4; ++r) { float v = accA[mt][r]; ls += v; lq += v * v; }
    float mean, istd;
    block_stats(ls, lq, sRed, tid, 1.0f / 2048.0f, mean, istd);
    #pragma unroll
    for (int mt = 0; mt < 2; ++mt) {
        bf16x4 pk;
        #pragma unroll
        for (int r = 0; r < 4; ++r) {
            float y = (accA[mt][r] - mean) * istd;
            pk[r] = (short)f2b(y > 0.f ? y : 0.f);
        }
        *(bf16x4*)(&X1T[wave * 16 + l16][mt * 16 + quad * 4]) = pk;
    }
    __syncthreads();

    f32x4 accB[2] = {};
    {
        bf16x8 b = *(const bf16x8*)(&X1T[wave * 16 + l16][quad * 8]);
        #pragma unroll
        for (int mt = 0; mt < 2; ++mt) {
            bf16x8 a = *(const bf16x8*)(&sS[mt * 16 + l16][quad * 8]);
            accB[mt] = __builtin_amdgcn_mfma_f32_16x16x32_bf16(a, b, accB[mt], 0, 0, 0);
        }
    }
    ls = 0.f; lq = 0.f;
    #pragma unroll
    for (int mt = 0; mt < 2; ++mt)
        #pragma unroll
        for (int r = 0; r < 4; ++r) { float v = accB[mt][r]; ls += v; lq += v * v; }
    block_stats(ls, lq, sRed, tid, 1.0f / 2048.0f, mean, istd);

    unsigned short* outp = FMS + (size_t)t * 8192 + g * 2048;
    const int d = wave * 16 + l16;
    #pragma unroll
    for (int mt = 0; mt < 2; ++mt)
        #pragma unroll
        for (int r = 0; r < 4; ++r) {
            float y = (accB[mt][r] - mean) * istd;
            outp[(mt * 16 + quad * 4 + r) * 64 + d] = f2b(y > 0.f ? y : 0.f);
        }
}

// ---------------------------------------------------------------------------
// Phase 2 cls (MFMA): v = relu(LN2d(f@vW)); k = kw·v^T + kb;
// sc = softmax(q@k/8); fc = relu(LN2d(sc@v))
// ---------------------------------------------------------------------------
__global__ __launch_bounds__(256) void p2_cls_kernel(
    const float* __restrict__ feats,
    const unsigned short* __restrict__ Y2,     // (BN,20480) bf16 [vW^T | q]
    const float* __restrict__ kwp,             // (128,64) fp32
    const float* __restrict__ kbp,             // (128) fp32
    unsigned short* __restrict__ FC)
{
    const int t = blockIdx.x, g = blockIdx.y;
    const int tid = threadIdx.x;
    const int wave = tid >> 6, lane = tid & 63;
    const int l16 = lane & 15, quad = lane >> 4;

    __shared__ short fB[32][72];
    __shared__ short Vt[64][72];
    __shared__ short kw[32][72];
    __shared__ short vRM[32][72];
    __shared__ short vT[64][40];
    __shared__ short kT[32][40];
    __shared__ short sQ[32][40];
    __shared__ short sSC[32][40];
    __shared__ float sKB[32];
    __shared__ float sRed[16];

    {
        const float* fp = feats + (size_t)(t * NG + g) * 2048 + tid * 8;
        float4 x0 = ((const float4*)fp)[0];
        float4 x1 = ((const float4*)fp)[1];
        bf16x8 v;
        v[0]=(short)f2b(x0.x); v[1]=(short)f2b(x0.y); v[2]=(short)f2b(x0.z); v[3]=(short)f2b(x0.w);
        v[4]=(short)f2b(x1.x); v[5]=(short)f2b(x1.y); v[6]=(short)f2b(x1.z); v[7]=(short)f2b(x1.w);
        *(bf16x8*)(&fB[tid >> 3][(tid & 7) * 8]) = v;
    }
    {
        const unsigned short* mp = Y2 + (size_t)t * 20480 + g * 4096 + tid * 16;
        bf16x8 v0 = ((const bf16x8*)mp)[0];
        bf16x8 v1 = ((const bf16x8*)mp)[1];
        const int d = tid >> 2, c0 = (tid & 3) * 16;
        *(bf16x8*)(&Vt[d][c0])     = v0;
        *(bf16x8*)(&Vt[d][c0 + 8]) = v1;
    }
    {
        const float* kp = kwp + (size_t)g * 2048 + tid * 8;
        float4 x0 = ((const float4*)kp)[0];
        float4 x1 = ((const float4*)kp)[1];
        bf16x8 v;
        v[0]=(short)f2b(x0.x); v[1]=(short)f2b(x0.y); v[2]=(short)f2b(x0.z); v[3]=(short)f2b(x0.w);
        v[4]=(short)f2b(x1.x); v[5]=(short)f2b(x1.y); v[6]=(short)f2b(x1.z); v[7]=(short)f2b(x1.w);
        *(bf16x8*)(&kw[tid >> 3][(tid & 7) * 8]) = v;
    }
    {
        const unsigned short* qp = Y2 + (size_t)t * 20480 + 16384 + g * 1024 + tid * 4;
        *(bf16x4*)(&sQ[tid >> 3][(tid & 7) * 4]) = *(const bf16x4*)qp;
    }
    if (tid < 32) sKB[tid] = kbp[g * 32 + tid];
    __syncthreads();

    f32x4 accA[2] = {};
    #pragma unroll
    for (int ks = 0; ks < 64; ks += 32) {
        bf16x8 b = *(const bf16x8*)(&Vt[wave * 16 + l16][ks + quad * 8]);
        #pragma unroll
        for (int mt = 0; mt < 2; ++mt) {
            bf16x8 a = *(const bf16x8*)(&fB[mt * 16 + l16][ks + quad * 8]);
            accA[mt] = __builtin_amdgcn_mfma_f32_16x16x32_bf16(a, b, accA[mt], 0, 0, 0);
        }
    }
    float ls = 0.f, lq = 0.f;
    #pragma unroll
    for (int mt = 0; mt < 2; ++mt)
        #pragma unroll
        for (int r = 0; r < 4; ++r) { float v = accA[mt][r]; ls += v; lq += v * v; }
    float mean, istd;
    block_stats(ls, lq, sRed, tid, 1.0f / 2048.0f, mean, istd);
    {
        const int d = wave * 16 + l16;
        #pragma unroll
        for (int mt = 0; mt < 2; ++mt) {
            bf16x4 pk;
            #pragma unroll
            for (int r = 0; r < 4; ++r) {
                float y = (accA[mt][r] - mean) * istd;
                unsigned short u = f2b(y > 0.f ? y : 0.f);
                pk[r] = (short)u;
                vRM[mt * 16 + quad * 4 + r][d] = (short)u;
            }
            *(bf16x4*)(&vT[d][mt * 16 + quad * 4]) = pk;
        }
    }
    __syncthreads();

    {   // k[i][p] = kw[i]·v[p] + kb
        const int it = wave >> 1, pt = wave & 1;
        f32x4 accK = {};
        #pragma unroll
        for (int ks = 0; ks < 64; ks += 32) {
            bf16x8 a = *(const bf16x8*)(&kw[it * 16 + l16][ks + quad * 8]);
            bf16x8 b = *(const bf16x8*)(&vRM[pt * 16 + l16][ks + quad * 8]);
            accK = __builtin_amdgcn_mfma_f32_16x16x32_bf16(a, b, accK, 0, 0, 0);
        }
        bf16x4 pk;
        #pragma unroll
        for (int r = 0; r < 4; ++r)
            pk[r] = (short)f2b(accK[r] + sKB[it * 16 + quad * 4 + r]);
        *(bf16x4*)(&kT[pt * 16 + l16][it * 16 + quad * 4]) = pk;
    }
    __syncthreads();

    if (wave < 2) {   // logits + softmax
        f32x4 accL[2] = {};
        bf16x8 a = *(const bf16x8*)(&sQ[wave * 16 + l16][quad * 8]);
        #pragma unroll
        for (int pt = 0; pt < 2; ++pt) {
            bf16x8 b = *(const bf16x8*)(&kT[pt * 16 + l16][quad * 8]);
            accL[pt] = __builtin_amdgcn_mfma_f32_16x16x32_bf16(a, b, accL[pt], 0, 0, 0);
        }
        #pragma unroll
        for (int r = 0; r < 4; ++r) {
            float a0 = accL[0][r] * 0.125f, a1 = accL[1][r] * 0.125f;
            float mx = fmaxf(a0, a1);
            #pragma unroll
            for (int m = 1; m < 16; m <<= 1) mx = fmaxf(mx, __shfl_xor(mx, m, 64));
            a0 = __expf(a0 - mx); a1 = __expf(a1 - mx);
            float sum = a0 + a1;
            #pragma unroll
            for (int m = 1; m < 16; m <<= 1) sum += __shfl_xor(sum, m, 64);
            const float inv_s = 1.0f / sum;
            const int o = wave * 16 + quad * 4 + r;
            sSC[o][l16]      = (short)f2b(a0 * inv_s);
            sSC[o][16 + l16] = (short)f2b(a1 * inv_s);
        }
    }
    __syncthreads();

    f32x4 accB[2] = {};
    {
        bf16x8 b = *(const bf16x8*)(&vT[wave * 16 + l16][quad * 8]);
        #pragma unroll
        for (int mt = 0; mt < 2; ++mt) {
            bf16x8 a = *(const bf16x8*)(&sSC[mt * 16 + l16][quad * 8]);
            accB[mt] = __builtin_amdgcn_mfma_f32_16x16x32_bf16(a, b, accB[mt], 0, 0, 0);
        }
    }
    ls = 0.f; lq = 0.f;
    #pragma unroll
    for (int mt = 0; mt < 2; ++mt)
        #pragma unroll
        for (int r = 0; r < 4; ++r) { float v = accB[mt][r]; ls += v; lq += v * v; }
    block_stats(ls, lq, sRed, tid, 1.0f / 2048.0f, mean, istd);

    unsigned short* outp = FC + (size_t)t * 8192 + g * 2048;
    const int d = wave * 16 + l16;
    #pragma unroll
    for (int mt = 0; mt < 2; ++mt)
        #pragma unroll
        for (int r = 0; r < 4; ++r) {
            float y = (accB[mt][r] - mean) * istd;
            outp[(mt * 16 + quad * 4 + r) * 64 + d] = f2b(y > 0.f ? y : 0.f);
        }
}

// ---------------------------------------------------------------------------
// Final: reduce split-K partials, residual add, affine LN over 256, fp32 out.
// ---------------------------------------------------------------------------
__global__ __launch_bounds__(256) void final_ln_kernel(
    const float* __restrict__ qv,
    const float* __restrict__ MSP,   // (8, BN, 256) fp32 partials
    const float* __restrict__ CLP,
    const float* __restrict__ Wv_b,
    const float* __restrict__ Wv2_b,
    const float* __restrict__ lnA_w,
    const float* __restrict__ lnA_b,
    const float* __restrict__ lnB_w,
    const float* __restrict__ lnB_b,
    float* __restrict__ out)
{
    __shared__ float sRed[16];
    const int t = blockIdx.x;
    const int br = blockIdx.y;
    const int c = threadIdx.x;
    const float* P = br ? CLP : MSP;
    const float* bias = br ? Wv2_b : Wv_b;
    const float* lw = br ? lnB_w : lnA_w;
    const float* lb = br ? lnB_b : lnA_b;

    float x = qv[t * 256 + c] + bias[c];
    #pragma unroll
    for (int s = 0; s < 8; ++s) x += P[(size_t)s * (BN * 256) + t * 256 + c];

    float mean, istd;
    block_stats(x, x * x, sRed, c, 1.0f / 256.0f, mean, istd);
    out[(size_t)br * (BN * 256) + t * 256 + c] = (x - mean) * istd * lw[c] + lb[c];
}

// ---------------------------------------------------------------------------
extern "C" void kernel_launch(void* const* d_in, const int* in_sizes, int n_in,
                              void* d_out, int out_size, void* d_ws, size_t ws_size,
                              hipStream_t stream) {
    const float* feats = (const float*)d_in[0];
    const float* qv    = (const float*)d_in[1];
    const float* m_w   = (const float*)d_in[7];
    const float* m_b   = (const float*)d_in[8];
    const float* s_w   = (const float*)d_in[9];
    const float* s_b   = (const float*)d_in[10];
    const float* q_w   = (const float*)d_in[11];
    const float* q_b   = (const float*)d_in[12];
    const float* v_w   = (const float*)d_in[13];
    const float* v_b   = (const float*)d_in[14];
    const float* k_w   = (const float*)d_in[15];
    const float* k_b   = (const float*)d_in[16];
    const float* Wv_w  = (const float*)d_in[17];
    const float* Wv_b  = (const float*)d_in[18];
    const float* Wv2_w = (const float*)d_in[19];
    const float* Wv2_b = (const float*)d_in[20];
    const float* lnA_w = (const float*)d_in[21];
    const float* lnA_b = (const float*)d_in[22];
    const float* lnB_w = (const float*)d_in[23];
    const float* lnB_b = (const float*)d_in[24];

    char* ws = (char*)d_ws;
    // Workspace (176.9 MB peak):
    //  [0, 98.3M)       Y1 (fused gen out, 2400x20480 bf16) -> later MSP/CLP/WvB
    //  [98.3M, 137.6M)  FMS
    //  [137.6M, 176.9M) FC; transient preps live here until p2_cls
    const size_t OFF_Y1  = 0;
    const size_t OFF_FMS = 98304000;
    const size_t OFF_FC  = 137625600;

    unsigned short* Y1  = (unsigned short*)(ws + OFF_Y1);
    unsigned short* FMS = (unsigned short*)(ws + OFF_FMS);
    unsigned short* FC  = (unsigned short*)(ws + OFF_FC);
    // transient preps in FC slot (22.4 MB <= 39.3 MB; all dead before p2_cls)
    unsigned short* W1   = (unsigned short*)(ws + OFF_FC);               // 10,485,760  [m_wP | s_wB]
    unsigned short* W2   = (unsigned short*)(ws + OFF_FC + 10485760);    // 10,485,760  [v_wP | q_wB]
    unsigned short* qv_B = (unsigned short*)(ws + OFF_FC + 20971520);    //  1,228,800
    float* b1 = (float*)(ws + OFF_FC + 22200320);                        //     81,920  [m_bP | s_b]
    float* b2 = (float*)(ws + OFF_FC + 22282240);                        //     81,920  [v_bP | q_b]
    // post-p2_cls region (Y1 dead): splitK=8 partials + bf16 proj weights
    float* MSP = (float*)(ws + 0);                                       // 19,660,800
    float* CLP = (float*)(ws + 19660800);                                // 19,660,800
    unsigned short* WvB  = (unsigned short*)(ws + 39321600);             //  4,194,304
    unsigned short* Wv2B = (unsigned short*)(ws + 43515904);             //  4,194,304

    const dim3 blk(256);
    // preps
    prep_perm_kernel<<<4096, blk, 0, stream>>>(m_w, m_b, W1, b1);
    prep_perm_kernel<<<4096, blk, 0, stream>>>(v_w, v_b, W2, b2);
    prep_flat_kernel<<<dim3(512, 3), blk, 0, stream>>>(
        s_w, W1 + 16384 * 256, 4096 * 256,
        q_w, W2 + 16384 * 256, 4096 * 256,
        qv,  qv_B,             BN * 256);
    copy_bias_kernel<<<dim3(16, 2), blk, 0, stream>>>(s_b, b1 + 16384, q_b, b2 + 16384);
    // reg branch: fused M+S generator (N=20480), then p2
    gemm_nt_kernel<0><<<dim3(38, 320), blk, 0, stream>>>(qv_B, W1, b1, Y1, BN, 20480, 256, 256);
    p2_reg_kernel<<<dim3(BN, NG), blk, 0, stream>>>(feats, Y1, FMS);
    // cls branch (reuse Y1)
    gemm_nt_kernel<0><<<dim3(38, 320), blk, 0, stream>>>(qv_B, W2, b2, Y1, BN, 20480, 256, 256);
    p2_cls_kernel<<<dim3(BN, NG), blk, 0, stream>>>(feats, Y1, k_w, k_b, FC);
    // projections: bf16 weights into dead Y1 region, 64-tile splitK=8
    prep_flat_kernel<<<dim3(1024, 2), blk, 0, stream>>>(
        Wv_w, WvB, 256 * 8192, Wv2_w, Wv2B, 256 * 8192, nullptr, nullptr, 0);
    gemm_nt_kernel<2><<<dim3(38, 4, 8), blk, 0, stream>>>(FMS, WvB,  nullptr, MSP, BN, 256, 8192, 1024);
    gemm_nt_kernel<2><<<dim3(38, 4, 8), blk, 0, stream>>>(FC,  Wv2B, nullptr, CLP, BN, 256, 8192, 1024);
    final_ln_kernel<<<dim3(BN, 2), blk, 0, stream>>>(qv, MSP, CLP, Wv_b, Wv2_b,
                                                     lnA_w, lnA_b, lnB_w, lnB_b,
                                                     (float*)d_out);
}